// Round 14
// baseline (255.642 us; speedup 1.0000x reference)
//
#include <hip/hip_runtime.h>
#include <stdint.h>
#include <math.h>

#define NN 8192        // nodes
#define NE 262144      // edges
#define WPR 256        // 32-bit words per dense adjacency row

struct TFKey { uint32_t a, b; };

// JAX threefry2x32 (rot 13,15,26,6 / 17,29,16,24; 20 rounds)
__host__ __device__ static inline void tf2x32(uint32_t k0, uint32_t k1,
                                              uint32_t x0, uint32_t x1,
                                              uint32_t* o0, uint32_t* o1) {
  uint32_t ks2 = k0 ^ k1 ^ 0x1BD11BDAu;
#define TF_ROT(x, r) (((x) << (r)) | ((x) >> (32 - (r))))
#define TF_R(r) { x0 += x1; x1 = TF_ROT(x1, r); x1 ^= x0; }
  x0 += k0; x1 += k1;
  TF_R(13) TF_R(15) TF_R(26) TF_R(6)
  x0 += k1;  x1 += ks2 + 1u;
  TF_R(17) TF_R(29) TF_R(16) TF_R(24)
  x0 += ks2; x1 += k0 + 2u;
  TF_R(13) TF_R(15) TF_R(26) TF_R(6)
  x0 += k0;  x1 += k1 + 3u;
  TF_R(17) TF_R(29) TF_R(16) TF_R(24)
  x0 += k1;  x1 += ks2 + 4u;
  TF_R(13) TF_R(15) TF_R(26) TF_R(6)
  x0 += ks2; x1 += k0 + 5u;
  *o0 = x0; *o1 = x1;
#undef TF_R
#undef TF_ROT
}

// JAX partitionable 32-bit random_bits at flat index n: bits = o0^o1 @ (0,n);
// uniform f32 = bitcast((bits>>9)|0x3f800000) - 1.0f  (exact 2^-23 grid)
__device__ static inline float tf_uniform(TFKey k, uint32_t n) {
  uint32_t o0, o1;
  tf2x32(k.a, k.b, 0u, n, &o0, &o1);
  uint32_t bits = o0 ^ o1;
  return __uint_as_float((bits >> 9) | 0x3f800000u) - 1.0f;
}

// ---- build dense adjacency + per-row degree in one pass.
//      int64/int32 layout decided per-wave via ballot (P(wrong) ~ 8192^-64).
//      atomicOr's old value detects first-set bits -> deg increment. ----
__global__ __launch_bounds__(256) void k_build(const int* __restrict__ e,
                                               uint32_t* __restrict__ dense,
                                               uint32_t* __restrict__ deg) {
  int ed = blockIdx.x * 256 + threadIdx.x;
  const unsigned long long* p64 = (const unsigned long long*)e;
  unsigned long long v = p64[ed];
  bool int32mode = (__ballot(v >= 8192ull) != 0ull);
  int r, c;
  if (int32mode) { r = e[ed]; c = e[ed + NE]; }
  else { const long long* p = (const long long*)e; r = (int)p[ed]; c = (int)p[ed + NE]; }
  uint32_t bit = 1u << (c & 31);
  uint32_t old = atomicOr(&dense[(size_t)r * WPR + (c >> 5)], bit);
  if (!(old & bit)) atomicAdd(&deg[r], 1u);   // unique edge -> degree
}

// ---- exclusive scan of deg[8192] -> rowptr[8193]; single block,
//      vectorized uint4 loads (8 independent 16B loads per thread) ----
__global__ __launch_bounds__(256) void k_scan(const uint32_t* __restrict__ deg,
                                              uint32_t* __restrict__ rowptr) {
  __shared__ uint32_t part[256];
  int t = threadIdx.x;
  uint32_t d[32];
  const uint4* dv = (const uint4*)(deg + t * 32);
#pragma unroll
  for (int q = 0; q < 8; ++q) {               // independent vector loads
    uint4 v = dv[q];
    d[q * 4] = v.x; d[q * 4 + 1] = v.y; d[q * 4 + 2] = v.z; d[q * 4 + 3] = v.w;
  }
  uint32_t loc[32];
  uint32_t s = 0;
#pragma unroll
  for (int k = 0; k < 32; ++k) { loc[k] = s; s += d[k]; }
  part[t] = s;
  __syncthreads();
  for (int off = 1; off < 256; off <<= 1) {
    uint32_t v = (t >= off) ? part[t - off] : 0u;
    __syncthreads();
    part[t] += v;
    __syncthreads();
  }
  uint32_t base = (t == 0) ? 0u : part[t - 1];
#pragma unroll
  for (int k = 0; k < 32; ++k) rowptr[t * 32 + k] = base + loc[k];
  if (t == 255) rowptr[8192] = part[255];
}

// ---- CSR pack[e] = (i<<13)|j from dense bitmask; wave-per-row, ascending ----
__global__ __launch_bounds__(256) void k_fill(const uint32_t* __restrict__ dense,
                                              const uint32_t* __restrict__ rowptr,
                                              uint32_t* __restrict__ pack) {
  int lane = threadIdx.x & 63;
  int i = blockIdx.x * 4 + (threadIdx.x >> 6);
  const uint4* row = (const uint4*)(dense + (size_t)i * WPR);
  uint4 v = row[lane];
  uint32_t w[4] = { v.x, v.y, v.z, v.w };
  int cnt = __popc(w[0]) + __popc(w[1]) + __popc(w[2]) + __popc(w[3]);
  int pre = cnt;
  for (int s = 1; s < 64; s <<= 1) {
    int o = __shfl_up(pre, s, 64);
    if (lane >= s) pre += o;
  }
  pre -= cnt;
  uint32_t pos = rowptr[i] + (uint32_t)pre;
  uint32_t ibase = ((uint32_t)i << 13);
  for (int wi = 0; wi < 4; ++wi) {
    uint32_t word = w[wi];
    while (word) {
      int b = __ffs(word) - 1;
      word &= word - 1;
      pack[pos++] = ibase | (uint32_t)(lane * 128 + wi * 32 + b);
    }
  }
}

// ---- fused: blocks [0,GB) do H = A@W (f64 dual-acc -> f32); blocks
//      [GB,GB+NN/256) do dinv[i] = f32 rsqrt(1 + cnt[i]) one-liner. ----
template<int K, int N>
__global__ __launch_bounds__(256) void k_dg(const float* __restrict__ A,
                                            const float* __restrict__ Wb,
                                            float* __restrict__ H,
                                            const uint32_t* __restrict__ cnt,
                                            float* __restrict__ dinv) {
  constexpr int GB = NN * N / 256;
  if (blockIdx.x < GB) {
    int t = blockIdx.x * 256 + threadIdx.x;
    int i = t / N, c = t % N;
    double a0 = 0.0, a1 = 0.0;
#pragma unroll 8
    for (int k = 0; k < K; k += 2) {
      a0 += (double)A[(size_t)i * K + k] * (double)Wb[(size_t)k * N + c];
      a1 += (double)A[(size_t)i * K + k + 1] * (double)Wb[(size_t)(k + 1) * N + c];
    }
    H[t] = (float)(a0 + a1);
  } else {
    int i = (blockIdx.x - GB) * 256 + threadIdx.x;
    if (i < NN) dinv[i] = (float)(1.0 / sqrt((double)(cnt[i] + 1)));
  }
}

// ---- z_i = dropout(relu(sum_j f32(di*dj)*h_j + f32(di*di)*h_i + b)) ----
template<int D>
__global__ __launch_bounds__(256) void k_agg(const uint32_t* __restrict__ rowptr,
                                             const uint32_t* __restrict__ pack,
                                             const uint8_t* __restrict__ mask,
                                             const float* __restrict__ h,
                                             const float* __restrict__ dinv,
                                             const float* __restrict__ bias,
                                             TFKey kd, float* __restrict__ zout) {
  int lane = threadIdx.x & 63;
  int i = blockIdx.x * 4 + (threadIdx.x >> 6);
  bool act = lane < D;
  float di = dinv[i];
  uint32_t s0 = rowptr[i], s1 = rowptr[i + 1];
  double a0 = 0.0, a1 = 0.0;
  uint32_t e = s0;
  for (; e + 1 < s1; e += 2) {                // dual acc: half the serial chain
    int j0 = pack[e] & 8191, j1 = pack[e + 1] & 8191;
    bool m0 = !mask || mask[e], m1 = !mask || mask[e + 1];
    if (act) {
      if (m0) { float c0 = di * dinv[j0]; a0 += (double)c0 * (double)h[(size_t)j0 * D + lane]; }
      if (m1) { float c1 = di * dinv[j1]; a1 += (double)c1 * (double)h[(size_t)j1 * D + lane]; }
    }
  }
  if (e < s1 && (!mask || mask[e]) && act) {
    int j = pack[e] & 8191;
    float c = di * dinv[j];
    a0 += (double)c * (double)h[(size_t)j * D + lane];
  }
  if (act) {
    double acc = a0 + a1;
    float cI = di * di;                       // +I diagonal term, f32
    acc += (double)cI * (double)h[(size_t)i * D + lane];
    float s = (float)acc;                     // matmul result rounded f32
    float pre = fmaxf(s + bias[lane], 0.0f);  // bias + relu (f32)
    float u = tf_uniform(kd, (uint32_t)(i * D + lane));
    zout[(size_t)i * D + lane] = (u < 0.9f) ? (pre / 0.9f) : 0.0f;
  }
}

// ---- edge-parallel resample; also counts survivors per row into cnt ----
__global__ __launch_bounds__(256) void k_sample_e(const uint32_t* __restrict__ rowptr,
                                                  const uint32_t* __restrict__ pack,
                                                  const float* __restrict__ z,
                                                  TFKey kb,
                                                  uint8_t* __restrict__ mask,
                                                  uint32_t* __restrict__ cnt) {
  uint32_t e = blockIdx.x * 256 + threadIdx.x;
  uint32_t nnz = rowptr[8192];
  if (e >= nnz) return;
  uint32_t n = pack[e];                       // (i<<13)|j == threefry counter
  uint32_t i = n >> 13, j = n & 8191;
  const float4* zi = (const float4*)(z + (size_t)i * 64);
  const float4* zj = (const float4*)(z + (size_t)j * 64);
  double p0 = 0.0, p1 = 0.0, p2 = 0.0, p3 = 0.0;
#pragma unroll
  for (int q = 0; q < 16; q += 2) {
    float4 a = zi[q], b = zj[q];
    float4 c = zi[q + 1], d = zj[q + 1];
    p0 += (double)a.x * (double)b.x + (double)a.y * (double)b.y;
    p1 += (double)a.z * (double)b.z + (double)a.w * (double)b.w;
    p2 += (double)c.x * (double)d.x + (double)c.y * (double)d.y;
    p3 += (double)c.z * (double)d.z + (double)c.w * (double)d.w;
  }
  double p = (p0 + p1) + (p2 + p3);
  float dot32 = (float)p;                     // ref's f32 z@z.T entry
  float prob = (float)(1.0 / (1.0 + exp(-(double)dot32)));  // identical formula
  float u = tf_uniform(kb, n);
  uint8_t mb = (u < prob) ? 1u : 0u;
  mask[e] = mb;
  if (mb) atomicAdd(&cnt[i], 1u);             // surviving-degree for next dinv
}

extern "C" void kernel_launch(void* const* d_in, const int* in_sizes, int n_in,
                              void* d_out, int out_size, void* d_ws, size_t ws_size,
                              hipStream_t stream) {
  (void)in_sizes; (void)n_in; (void)out_size; (void)ws_size;
  const float* x  = (const float*)d_in[0];
  const float* W0 = (const float*)d_in[1];
  const float* b0 = (const float*)d_in[2];
  const float* W1 = (const float*)d_in[3];
  const float* b1 = (const float*)d_in[4];
  const float* W2 = (const float*)d_in[5];
  const float* b2 = (const float*)d_in[6];
  const int* ei = (const int*)d_in[7];
  float* out = (float*)d_out;                // output is float32

  // Workspace (~10.7 MB): dense dies after k_fill; f32 h/z overlay it.
  // deg/cnt0/cnt1 contiguous after dense: ONE memset zeroes all four.
  uint8_t* base = (uint8_t*)d_ws;
  uint32_t* dense = (uint32_t*)(base);                       // [0, 8 MB) build
  float* h        = (float*)(base);                          // [0, 2 MB) layers
  float* z        = (float*)(base + 2097152);                // [2, 4 MB)
  uint32_t* deg   = (uint32_t*)(base + 8388608);             // 32 KB (zeroed)
  uint32_t* cnt0  = (uint32_t*)(base + 8388608 + 32768);     // 32 KB (zeroed)
  uint32_t* cnt1  = (uint32_t*)(base + 8388608 + 65536);     // 32 KB (zeroed)
  uint32_t* rowptr= (uint32_t*)(base + 8388608 + 98304);     // 32 KB+4
  uint32_t* pack  = (uint32_t*)(base + 8388608 + 163840);    // 1 MB
  uint8_t*  mask  = (uint8_t*)(base + 8388608 + 1212416);    // 256 KB
  float*    dinv  = (float*)(base + 8388608 + 1474560);      // 32 KB

  // JAX partitionable key chain: k_i = fold_in(key(42), i) = cipher((0,42),(0,i));
  // foldlike split: kd = full pair @ (0,0), kb = full pair @ (0,1)
  TFKey kd[3], kb[3];
  for (uint32_t i = 0; i < 3; ++i) {
    uint32_t la, lb;
    tf2x32(0u, 42u, 0u, i, &la, &lb);
    tf2x32(la, lb, 0u, 0u, &kd[i].a, &kd[i].b);
    tf2x32(la, lb, 0u, 1u, &kb[i].a, &kb[i].b);
  }

  // one memset covers dense (8MB) + deg + cnt0 + cnt1 (96KB)
  (void)hipMemsetAsync(dense, 0, (size_t)NN * WPR * 4 + 98304, stream);
  k_build<<<NE / 256, 256, 0, stream>>>(ei, dense, deg);
  k_scan <<<1, 256, 0, stream>>>(deg, rowptr);
  k_fill <<<NN / 4, 256, 0, stream>>>(dense, rowptr, pack);
  // dense dead; h/z overlay it

  // layer 0: fused {gemm x@W0, dinv from deg}, agg, resample(count -> cnt0)
  k_dg<128, 64><<<NN * 64 / 256 + NN / 256, 256, 0, stream>>>(x, W0, h, deg, dinv);
  k_agg<64><<<NN / 4, 256, 0, stream>>>(rowptr, pack, nullptr, h, dinv, b0, kd[0], z);
  k_sample_e<<<NE / 256, 256, 0, stream>>>(rowptr, pack, z, kb[0], mask, cnt0);

  // layer 1: dinv from cnt0; resample counts into cnt1
  k_dg<64, 64><<<NN * 64 / 256 + NN / 256, 256, 0, stream>>>(z, W1, h, cnt0, dinv);
  k_agg<64><<<NN / 4, 256, 0, stream>>>(rowptr, pack, mask, h, dinv, b1, kd[1], z);
  k_sample_e<<<NE / 256, 256, 0, stream>>>(rowptr, pack, z, kb[1], mask, cnt1);

  // layer 2: dinv from cnt1 -> f32 output
  k_dg<64, 32><<<NN * 32 / 256 + NN / 256, 256, 0, stream>>>(z, W2, h, cnt1, dinv);
  k_agg<32><<<NN / 4, 256, 0, stream>>>(rowptr, pack, mask, h, dinv, b2, kd[2], out);
}

// Round 15
// 234.382 us; speedup vs baseline: 1.0907x; 1.0907x over previous
//
#include <hip/hip_runtime.h>
#include <stdint.h>
#include <math.h>

#define NN 8192        // nodes
#define NE 262144      // edges
#define WPR 256        // 32-bit words per dense adjacency row

struct TFKey { uint32_t a, b; };

// JAX threefry2x32 (rot 13,15,26,6 / 17,29,16,24; 20 rounds)
__host__ __device__ static inline void tf2x32(uint32_t k0, uint32_t k1,
                                              uint32_t x0, uint32_t x1,
                                              uint32_t* o0, uint32_t* o1) {
  uint32_t ks2 = k0 ^ k1 ^ 0x1BD11BDAu;
#define TF_ROT(x, r) (((x) << (r)) | ((x) >> (32 - (r))))
#define TF_R(r) { x0 += x1; x1 = TF_ROT(x1, r); x1 ^= x0; }
  x0 += k0; x1 += k1;
  TF_R(13) TF_R(15) TF_R(26) TF_R(6)
  x0 += k1;  x1 += ks2 + 1u;
  TF_R(17) TF_R(29) TF_R(16) TF_R(24)
  x0 += ks2; x1 += k0 + 2u;
  TF_R(13) TF_R(15) TF_R(26) TF_R(6)
  x0 += k0;  x1 += k1 + 3u;
  TF_R(17) TF_R(29) TF_R(16) TF_R(24)
  x0 += k1;  x1 += ks2 + 4u;
  TF_R(13) TF_R(15) TF_R(26) TF_R(6)
  x0 += ks2; x1 += k0 + 5u;
  *o0 = x0; *o1 = x1;
#undef TF_R
#undef TF_ROT
}

// JAX partitionable 32-bit random_bits at flat index n: bits = o0^o1 @ (0,n);
// uniform f32 = bitcast((bits>>9)|0x3f800000) - 1.0f  (exact 2^-23 grid)
__device__ static inline float tf_uniform(TFKey k, uint32_t n) {
  uint32_t o0, o1;
  tf2x32(k.a, k.b, 0u, n, &o0, &o1);
  uint32_t bits = o0 ^ o1;
  return __uint_as_float((bits >> 9) | 0x3f800000u) - 1.0f;
}

// ---- build dense adjacency + per-row degree in one pass.
//      int64/int32 layout decided per-wave via ballot (P(wrong) ~ 8192^-64).
//      atomicOr's old value detects first-set bits -> deg increment. ----
__global__ __launch_bounds__(256) void k_build(const int* __restrict__ e,
                                               uint32_t* __restrict__ dense,
                                               uint32_t* __restrict__ deg) {
  int ed = blockIdx.x * 256 + threadIdx.x;
  const unsigned long long* p64 = (const unsigned long long*)e;
  unsigned long long v = p64[ed];
  bool int32mode = (__ballot(v >= 8192ull) != 0ull);
  int r, c;
  if (int32mode) { r = e[ed]; c = e[ed + NE]; }
  else { const long long* p = (const long long*)e; r = (int)p[ed]; c = (int)p[ed + NE]; }
  uint32_t bit = 1u << (c & 31);
  uint32_t old = atomicOr(&dense[(size_t)r * WPR + (c >> 5)], bit);
  if (!(old & bit)) atomicAdd(&deg[r], 1u);   // unique edge -> degree
}

// ---- exclusive scan of deg[8192] -> rowptr[8193]; single block,
//      vectorized uint4 loads (8 independent 16B loads per thread) ----
__global__ __launch_bounds__(256) void k_scan(const uint32_t* __restrict__ deg,
                                              uint32_t* __restrict__ rowptr) {
  __shared__ uint32_t part[256];
  int t = threadIdx.x;
  uint32_t d[32];
  const uint4* dv = (const uint4*)(deg + t * 32);
#pragma unroll
  for (int q = 0; q < 8; ++q) {               // independent vector loads
    uint4 v = dv[q];
    d[q * 4] = v.x; d[q * 4 + 1] = v.y; d[q * 4 + 2] = v.z; d[q * 4 + 3] = v.w;
  }
  uint32_t loc[32];
  uint32_t s = 0;
#pragma unroll
  for (int k = 0; k < 32; ++k) { loc[k] = s; s += d[k]; }
  part[t] = s;
  __syncthreads();
  for (int off = 1; off < 256; off <<= 1) {
    uint32_t v = (t >= off) ? part[t - off] : 0u;
    __syncthreads();
    part[t] += v;
    __syncthreads();
  }
  uint32_t base = (t == 0) ? 0u : part[t - 1];
#pragma unroll
  for (int k = 0; k < 32; ++k) rowptr[t * 32 + k] = base + loc[k];
  if (t == 255) rowptr[8192] = part[255];
}

// ---- CSR cols+rows from dense bitmask; wave-per-row, ascending cols ----
__global__ __launch_bounds__(256) void k_fill(const uint32_t* __restrict__ dense,
                                              const uint32_t* __restrict__ rowptr,
                                              uint16_t* __restrict__ cols,
                                              uint16_t* __restrict__ rows) {
  int lane = threadIdx.x & 63;
  int i = blockIdx.x * 4 + (threadIdx.x >> 6);
  const uint4* row = (const uint4*)(dense + (size_t)i * WPR);
  uint4 v = row[lane];
  uint32_t w[4] = { v.x, v.y, v.z, v.w };
  int cnt = __popc(w[0]) + __popc(w[1]) + __popc(w[2]) + __popc(w[3]);
  int pre = cnt;
  for (int s = 1; s < 64; s <<= 1) {
    int o = __shfl_up(pre, s, 64);
    if (lane >= s) pre += o;
  }
  pre -= cnt;
  uint32_t pos = rowptr[i] + (uint32_t)pre;
  for (int wi = 0; wi < 4; ++wi) {
    uint32_t word = w[wi];
    while (word) {
      int b = __ffs(word) - 1;
      word &= word - 1;
      cols[pos] = (uint16_t)(lane * 128 + wi * 32 + b);
      rows[pos] = (uint16_t)i;
      ++pos;
    }
  }
}

// ---- fused: blocks [0,GB) do H = A@W (f64 dual-acc -> f32); blocks
//      [GB,GB+NN/4) do dinv[i] = f32 rsqrt(1 + surviving-degree). ----
template<int K, int N>
__global__ __launch_bounds__(256) void k_dg(const float* __restrict__ A,
                                            const float* __restrict__ Wb,
                                            float* __restrict__ H,
                                            const uint32_t* __restrict__ rowptr,
                                            const uint8_t* __restrict__ mask,
                                            float* __restrict__ dinv) {
  constexpr int GB = NN * N / 256;
  if (blockIdx.x < GB) {
    int t = blockIdx.x * 256 + threadIdx.x;
    int i = t / N, c = t % N;
    double a0 = 0.0, a1 = 0.0;
#pragma unroll 8
    for (int k = 0; k < K; k += 2) {
      a0 += (double)A[(size_t)i * K + k] * (double)Wb[(size_t)k * N + c];
      a1 += (double)A[(size_t)i * K + k + 1] * (double)Wb[(size_t)(k + 1) * N + c];
    }
    H[t] = (float)(a0 + a1);
  } else {
    int lane = threadIdx.x & 63;
    int i = (blockIdx.x - GB) * 4 + (threadIdx.x >> 6);
    uint32_t s0 = rowptr[i], s1 = rowptr[i + 1];
    int c = 0;
    for (uint32_t e = s0 + lane; e < s1; e += 64) c += mask ? (int)mask[e] : 1;
    for (int s = 32; s; s >>= 1) c += __shfl_xor(c, s, 64);
    if (lane == 0) dinv[i] = (float)(1.0 / sqrt((double)(c + 1)));
  }
}

// ---- z_i = dropout(relu(sum_j f32(di*dj)*h_j + f32(di*di)*h_i + b)) ----
template<int D>
__global__ __launch_bounds__(256) void k_agg(const uint32_t* __restrict__ rowptr,
                                             const uint16_t* __restrict__ cols,
                                             const uint8_t* __restrict__ mask,
                                             const float* __restrict__ h,
                                             const float* __restrict__ dinv,
                                             const float* __restrict__ bias,
                                             TFKey kd, float* __restrict__ zout) {
  int lane = threadIdx.x & 63;
  int i = blockIdx.x * 4 + (threadIdx.x >> 6);
  bool act = lane < D;
  float di = dinv[i];
  uint32_t s0 = rowptr[i], s1 = rowptr[i + 1];
  double a0 = 0.0, a1 = 0.0;
  uint32_t e = s0;
  for (; e + 1 < s1; e += 2) {                // dual acc: half the serial chain
    int j0 = cols[e], j1 = cols[e + 1];
    bool m0 = !mask || mask[e], m1 = !mask || mask[e + 1];
    if (act) {
      if (m0) { float c0 = di * dinv[j0]; a0 += (double)c0 * (double)h[(size_t)j0 * D + lane]; }
      if (m1) { float c1 = di * dinv[j1]; a1 += (double)c1 * (double)h[(size_t)j1 * D + lane]; }
    }
  }
  if (e < s1 && (!mask || mask[e]) && act) {
    int j = cols[e];
    float c = di * dinv[j];
    a0 += (double)c * (double)h[(size_t)j * D + lane];
  }
  if (act) {
    double acc = a0 + a1;
    float cI = di * di;                       // +I diagonal term, f32
    acc += (double)cI * (double)h[(size_t)i * D + lane];
    float s = (float)acc;                     // matmul result rounded f32
    float pre = fmaxf(s + bias[lane], 0.0f);  // bias + relu (f32)
    float u = tf_uniform(kd, (uint32_t)(i * D + lane));
    zout[(size_t)i * D + lane] = (u < 0.9f) ? (pre / 0.9f) : 0.0f;
  }
}

// ---- edge-parallel resample: lane-per-edge, f64 dot via float4 loads ----
__global__ __launch_bounds__(256) void k_sample_e(const uint32_t* __restrict__ rowptr,
                                                  const uint16_t* __restrict__ rows,
                                                  const uint16_t* __restrict__ cols,
                                                  const float* __restrict__ z,
                                                  TFKey kb,
                                                  uint8_t* __restrict__ mask) {
  uint32_t e = blockIdx.x * 256 + threadIdx.x;
  uint32_t nnz = rowptr[8192];
  if (e >= nnz) return;
  uint32_t i = rows[e], j = cols[e];
  const float4* zi = (const float4*)(z + (size_t)i * 64);
  const float4* zj = (const float4*)(z + (size_t)j * 64);
  double p0 = 0.0, p1 = 0.0, p2 = 0.0, p3 = 0.0;
#pragma unroll
  for (int q = 0; q < 16; q += 2) {
    float4 a = zi[q], b = zj[q];
    float4 c = zi[q + 1], d = zj[q + 1];
    p0 += (double)a.x * (double)b.x + (double)a.y * (double)b.y;
    p1 += (double)a.z * (double)b.z + (double)a.w * (double)b.w;
    p2 += (double)c.x * (double)d.x + (double)c.y * (double)d.y;
    p3 += (double)c.z * (double)d.z + (double)c.w * (double)d.w;
  }
  double p = (p0 + p1) + (p2 + p3);
  float dot32 = (float)p;                     // ref's f32 z@z.T entry
  float prob = (float)(1.0 / (1.0 + exp(-(double)dot32)));  // identical formula
  uint32_t n = ((uint32_t)i << 13) | (uint32_t)j;  // flat index i*8192+j
  float u = tf_uniform(kb, n);
  mask[e] = (u < prob) ? 1u : 0u;
}

extern "C" void kernel_launch(void* const* d_in, const int* in_sizes, int n_in,
                              void* d_out, int out_size, void* d_ws, size_t ws_size,
                              hipStream_t stream) {
  (void)in_sizes; (void)n_in; (void)out_size; (void)ws_size;
  const float* x  = (const float*)d_in[0];
  const float* W0 = (const float*)d_in[1];
  const float* b0 = (const float*)d_in[2];
  const float* W1 = (const float*)d_in[3];
  const float* b1 = (const float*)d_in[4];
  const float* W2 = (const float*)d_in[5];
  const float* b2 = (const float*)d_in[6];
  const int* ei = (const int*)d_in[7];
  float* out = (float*)d_out;                // output is float32

  // Workspace (~10 MB): dense bitmask dies after k_fill; f32 h/z overlay it.
  // deg sits right after dense so ONE memset covers both.
  uint8_t* base = (uint8_t*)d_ws;
  uint32_t* dense = (uint32_t*)(base);                       // [0, 8 MB) build
  float* h        = (float*)(base);                          // [0, 2 MB) layers
  float* z        = (float*)(base + 2097152);                // [2, 4 MB)
  uint32_t* deg   = (uint32_t*)(base + 8388608);             // 32 KB (zeroed w/ dense)
  uint32_t* rowptr= (uint32_t*)(base + 8388608 + 65536);     // 32 KB+4
  uint16_t* cols  = (uint16_t*)(base + 8388608 + 131072);    // 512 KB
  uint16_t* rows  = (uint16_t*)(base + 8388608 + 655360);    // 512 KB
  uint8_t*  mask  = (uint8_t*)(base + 8388608 + 1179648);    // 256 KB
  float*    dinv  = (float*)(base + 8388608 + 1441792);      // 32 KB

  // JAX partitionable key chain: k_i = fold_in(key(42), i) = cipher((0,42),(0,i));
  // foldlike split: kd = full pair @ (0,0), kb = full pair @ (0,1)
  TFKey kd[3], kb[3];
  for (uint32_t i = 0; i < 3; ++i) {
    uint32_t la, lb;
    tf2x32(0u, 42u, 0u, i, &la, &lb);
    tf2x32(la, lb, 0u, 0u, &kd[i].a, &kd[i].b);
    tf2x32(la, lb, 0u, 1u, &kb[i].a, &kb[i].b);
  }

  // one memset covers dense (8MB) + deg (32KB)
  (void)hipMemsetAsync(dense, 0, (size_t)NN * WPR * 4 + 32768, stream);
  k_build<<<NE / 256, 256, 0, stream>>>(ei, dense, deg);
  k_scan <<<1, 256, 0, stream>>>(deg, rowptr);
  k_fill <<<NN / 4, 256, 0, stream>>>(dense, rowptr, cols, rows);
  // dense dead; h/z overlay it

  // layer 0: fused {gemm x@W0, dinv(all edges)}, then agg, then resample
  k_dg<128, 64><<<NN * 64 / 256 + NN / 4, 256, 0, stream>>>(x, W0, h, rowptr, nullptr, dinv);
  k_agg<64><<<NN / 4, 256, 0, stream>>>(rowptr, cols, nullptr, h, dinv, b0, kd[0], z);
  k_sample_e<<<NE / 256, 256, 0, stream>>>(rowptr, rows, cols, z, kb[0], mask);

  // layer 1
  k_dg<64, 64><<<NN * 64 / 256 + NN / 4, 256, 0, stream>>>(z, W1, h, rowptr, mask, dinv);
  k_agg<64><<<NN / 4, 256, 0, stream>>>(rowptr, cols, mask, h, dinv, b1, kd[1], z);
  k_sample_e<<<NE / 256, 256, 0, stream>>>(rowptr, rows, cols, z, kb[1], mask);

  // layer 2 -> f32 output
  k_dg<64, 32><<<NN * 32 / 256 + NN / 4, 256, 0, stream>>>(z, W2, h, rowptr, mask, dinv);
  k_agg<32><<<NN / 4, 256, 0, stream>>>(rowptr, cols, mask, h, dinv, b2, kd[2], out);
}